// Round 1
// baseline (296.785 us; speedup 1.0000x reference)
//
#include <hip/hip_runtime.h>
#include <math.h>

#define EPSF 1e-5f

typedef float float4v __attribute__((ext_vector_type(4)));

// ---------------------------------------------------------------------------
// k1: per-(b,c) plane -> row/col means -> strip pool (x + conv3 + conv7)/3 -> BN
// writes sp[b][c][0..127]  (l<64: h-strip, l>=64: w-strip)
// ---------------------------------------------------------------------------
__global__ __launch_bounds__(256) void k1_pool_strip(
    const float* __restrict__ x,
    const float* __restrict__ sph_w3, const float* __restrict__ sph_w7,
    const float* __restrict__ sph_g,  const float* __restrict__ sph_b,
    const float* __restrict__ sph_m,  const float* __restrict__ sph_v,
    const float* __restrict__ spw_w3, const float* __restrict__ spw_w7,
    const float* __restrict__ spw_g,  const float* __restrict__ spw_b,
    const float* __restrict__ spw_m,  const float* __restrict__ spw_v,
    float* __restrict__ sp)
{
    __shared__ __align__(16) float tile[64][68];   // stride 68: 16B-aligned rows
    __shared__ __align__(16) float rpart[256];     // rpart[r*4+q] row partials
    __shared__ float cpart[4][64];                 // per-wave col partials
    __shared__ float mh[64];   // row means (mean over w) -> x_h
    __shared__ float mw[64];   // col means (mean over h) -> x_w

    const int plane = blockIdx.x;          // b*256 + c
    const int c = plane & 255;
    const float* xp = x + (size_t)plane * 4096;
    const int t = threadIdx.x;
    const int r = t >> 2, q = t & 3;

    // coalesced: thread t loads bytes [64t, 64t+64) = 16 floats of row r
    const float4* src = (const float4*)(xp + r * 64 + q * 16);
    float4 v0 = src[0], v1 = src[1], v2 = src[2], v3 = src[3];
    float4* dst = (float4*)&tile[r][q * 16];
    dst[0] = v0; dst[1] = v1; dst[2] = v2; dst[3] = v3;
    // row partial sum (16 floats) computed from registers — free
    rpart[t] = (v0.x + v0.y + v0.z + v0.w) + (v1.x + v1.y + v1.z + v1.w)
             + (v2.x + v2.y + v2.z + v2.w) + (v3.x + v3.y + v3.z + v3.w);
    __syncthreads();

    // col partials: wave qw sums rows [16qw, 16qw+16) of column cc
    {
        const int cc = t & 63, qw = t >> 6;
        float s = 0.f;
        #pragma unroll
        for (int i = 0; i < 16; ++i) s += tile[qw * 16 + i][cc];  // conflict-free
        cpart[qw][cc] = s;
    }
    __syncthreads();

    if (t < 64) {
        float4 rp = ((const float4*)rpart)[t];     // ds_read_b128, conflict-free
        mh[t] = (rp.x + rp.y + rp.z + rp.w) * (1.f / 64.f);
        mw[t] = (cpart[0][t] + cpart[1][t] + cpart[2][t] + cpart[3][t]) * (1.f / 64.f);
    }
    __syncthreads();

    if (t < 128) {
        const int l = t & 63;
        const bool is_h = (t < 64);
        const float* m  = is_h ? mh     : mw;
        const float* w3 = is_h ? sph_w3 : spw_w3;
        const float* w7 = is_h ? sph_w7 : spw_w7;
        const float* g  = is_h ? sph_g  : spw_g;
        const float* bb = is_h ? sph_b  : spw_b;
        const float* mu = is_h ? sph_m  : spw_m;
        const float* vv = is_h ? sph_v  : spw_v;

        float v[7];
        #pragma unroll
        for (int j = 0; j < 7; ++j) {
            int idx = l - 3 + j;
            v[j] = (idx >= 0 && idx < 64) ? m[idx] : 0.f;
        }
        // cross-correlation (jax conv_general_dilated does not flip kernels)
        float c3 = w3[c*3+0]*v[2] + w3[c*3+1]*v[3] + w3[c*3+2]*v[4];
        float c7 = 0.f;
        #pragma unroll
        for (int j = 0; j < 7; ++j) c7 += w7[c*7+j]*v[j];

        float o = (v[3] + c3 + c7) * (1.f / 3.f);
        float scale = g[c] * rsqrtf(vv[c] + EPSF);
        o = (o - mu[c]) * scale + bb[c];
        sp[(size_t)plane * 128 + (is_h ? l : 64 + l)] = o;
    }
}

// ---------------------------------------------------------------------------
// k2: y[b][m][l] = hswish(bn1(conv1_w @ sp))   — 32*8*128 floats (128 KB) only.
// Attention matmuls moved into k3 (they are per-(b,c) and tiny).
// grid = (32 batches x 8 l-chunks of 16), 256 threads.
// ---------------------------------------------------------------------------
__global__ __launch_bounds__(256) void k2_y(
    const float* __restrict__ sp,
    const float* __restrict__ conv1_w,
    const float* __restrict__ bn1_g, const float* __restrict__ bn1_b,
    const float* __restrict__ bn1_m, const float* __restrict__ bn1_v,
    float* __restrict__ y)
{
    __shared__ float spc[256 * 16];   // spc[c][li]
    __shared__ float w1t[256 * 8];    // conv1_w transposed: w1t[c][m]

    const int b  = blockIdx.x >> 3;
    const int lc = blockIdx.x & 7;
    const int l0 = lc * 16;
    const int t = threadIdx.x;

    const float* spb = sp + (size_t)b * 256 * 128;

    // stage: sp slab (coalesced 64B segments), transposed weights (L2-hot, tiny)
    for (int j = t; j < 4096; j += 256) {
        int cc = j >> 4, li = j & 15;
        spc[j] = spb[cc * 128 + l0 + li];
    }
    for (int j = t; j < 2048; j += 256) {
        int cc = j >> 3, m = j & 7;
        w1t[j] = conv1_w[m * 256 + cc];
    }
    __syncthreads();

    // y[m][li] = hswish(bn1(sum_c w1[m][c] * sp[c][li]))
    if (t < 128) {
        const int m = t >> 4, li = t & 15;
        float acc = 0.f;
        for (int cc = 0; cc < 256; ++cc)
            acc += w1t[cc * 8 + m] * spc[cc * 16 + li];   // broadcast reads
        float scale = bn1_g[m] * rsqrtf(bn1_v[m] + EPSF);
        float val = (acc - bn1_m[m]) * scale + bn1_b[m];
        val = val * fminf(fmaxf(val + 3.f, 0.f), 6.f) * (1.f / 6.f);  // hswish
        y[(size_t)b * 1024 + m * 128 + l0 + li] = val;
    }
}

// ---------------------------------------------------------------------------
// k3: one block per (b,c) plane. Stage y[b] (4 KB, L2-hot), compute the 128
// attention values (sigmoid of 8-tap dots) once in LDS, then stream
// out = x * ah[h] * aw[w] with 4x float4 per thread. x loads are issued
// BEFORE the y-stage so the attention prologue hides under VMEM latency.
// Non-temporal stores keep x L3-resident (k1 wrote it there this iteration).
// ---------------------------------------------------------------------------
__global__ __launch_bounds__(256) void k3_apply(
    const float* __restrict__ x,
    const float* __restrict__ y,
    const float* __restrict__ convh_w, const float* __restrict__ convw_w,
    float* __restrict__ out)
{
    __shared__ float ys[8 * 128];   // y[b][m][l]
    __shared__ float att[128];      // [0..63] = ah, [64..127] = aw

    const int plane = blockIdx.x;          // b*256 + c
    const int b = plane >> 8, c = plane & 255;
    const int t = threadIdx.x;

    const float* xp = x + (size_t)plane * 4096;
    float* op = out + (size_t)plane * 4096;

    // issue the plane loads first — they stay in flight across the y stage
    float4 xv0 = ((const float4*)xp)[t];
    float4 xv1 = ((const float4*)xp)[t + 256];
    float4 xv2 = ((const float4*)xp)[t + 512];
    float4 xv3 = ((const float4*)xp)[t + 768];

    // stage y[b] (1024 floats, coalesced, L2-hot: 256 blocks share it)
    const float* yb = y + (size_t)b * 1024;
    for (int j = t; j < 1024; j += 256) ys[j] = yb[j];
    __syncthreads();

    // att[t] = sigmoid(sum_m wo[c][m] * y[b][m][l])
    if (t < 128) {
        const bool is_h = (t < 64);
        const int l = t & 63;
        const float* wo = (is_h ? convh_w : convw_w) + c * 8;   // uniform: s_loads
        const float* yrow = ys + (is_h ? l : 64 + l);
        float s = 0.f;
        #pragma unroll
        for (int m = 0; m < 8; ++m)
            s += wo[m] * yrow[m * 128];          // consecutive lanes: conflict-free
        att[t] = 1.f / (1.f + __expf(-s));
    }
    __syncthreads();

    // apply: float4 g covers (h = g>>4, w = (g&15)*4 .. +3)
    #pragma unroll
    for (int k = 0; k < 4; ++k) {
        const int g = k * 256 + t;
        const int h = g >> 4;
        const int w0 = (g & 15) * 4;
        const float4 xv = (k == 0) ? xv0 : (k == 1) ? xv1 : (k == 2) ? xv2 : xv3;
        const float ah = att[h];                         // 16-lane broadcast
        const float4 aw = *(const float4*)&att[64 + w0]; // b128, bcast groups
        float4v o;
        o.x = xv.x * ah * aw.x;
        o.y = xv.y * ah * aw.y;
        o.z = xv.z * ah * aw.z;
        o.w = xv.w * ah * aw.w;
        __builtin_nontemporal_store(o, (float4v*)op + g);
    }
}

// ---------------------------------------------------------------------------
extern "C" void kernel_launch(void* const* d_in, const int* in_sizes, int n_in,
                              void* d_out, int out_size, void* d_ws, size_t ws_size,
                              hipStream_t stream) {
    const float* x       = (const float*)d_in[0];
    const float* sph_w3  = (const float*)d_in[1];
    const float* sph_w7  = (const float*)d_in[2];
    const float* sph_g   = (const float*)d_in[3];
    const float* sph_b   = (const float*)d_in[4];
    const float* sph_m   = (const float*)d_in[5];
    const float* sph_v   = (const float*)d_in[6];
    const float* spw_w3  = (const float*)d_in[7];
    const float* spw_w7  = (const float*)d_in[8];
    const float* spw_g   = (const float*)d_in[9];
    const float* spw_b   = (const float*)d_in[10];
    const float* spw_m   = (const float*)d_in[11];
    const float* spw_v   = (const float*)d_in[12];
    const float* conv1_w = (const float*)d_in[13];
    const float* bn1_g   = (const float*)d_in[14];
    const float* bn1_b   = (const float*)d_in[15];
    const float* bn1_m   = (const float*)d_in[16];
    const float* bn1_v   = (const float*)d_in[17];
    const float* convh_w = (const float*)d_in[18];
    const float* convw_w = (const float*)d_in[19];

    float* ws = (float*)d_ws;
    float* sp = ws;                    // 32*256*128 = 1,048,576 floats (4 MB)
    float* yy = ws + 1048576;          // 32*8*128   =    32,768 floats (128 KB)

    const int B = 32, C = 256;

    k1_pool_strip<<<B * C, 256, 0, stream>>>(
        x, sph_w3, sph_w7, sph_g, sph_b, sph_m, sph_v,
        spw_w3, spw_w7, spw_g, spw_b, spw_m, spw_v, sp);

    k2_y<<<B * 8, 256, 0, stream>>>(
        sp, conv1_w, bn1_g, bn1_b, bn1_m, bn1_v, yy);

    k3_apply<<<B * C, 256, 0, stream>>>(x, yy, convh_w, convw_w, (float*)d_out);
}